// Round 3
// baseline (249.477 us; speedup 1.0000x reference)
//
#include <hip/hip_runtime.h>

// GNNEncoder fused MFMA kernel, round 3: wave-independent, barrier-free main loop.
// GEMM1: agg[i][f] (per s) = sum_j H[f][j] * An[i][j], A=H (regs), B=An (LDS frags)
// GEMM2: h2[f'][i] (per s) = sum_k W2[f'][k] * cat[k][i], A=W2 (regs), B=cat (h recomputed + catg LDS)
#define BN 16
#define SN 2048
#define NV 64
#define HD 32
#define SPW 8                 // s per wave
#define SPB (SPW * 4)         // 32 s per block
#define NCHUNK (SN / SPB)     // 64 chunks per b -> grid 1024
#define CATP 36               // catg row stride (72 B): 18 banks/row -> ~2-way, free

typedef short  bf8i  __attribute__((ext_vector_type(8)));
typedef __bf16 bfv8  __attribute__((ext_vector_type(8)));
typedef __bf16 bfv4  __attribute__((ext_vector_type(4)));
typedef float  f32x16 __attribute__((ext_vector_type(16)));
typedef float  f32x4  __attribute__((ext_vector_type(4)));

#define MFMA32(a, b, c) __builtin_amdgcn_mfma_f32_32x32x16_bf16( \
    __builtin_bit_cast(bf8i, (a)), __builtin_bit_cast(bf8i, (b)), (c), 0, 0, 0)

__global__ __launch_bounds__(256, 3) void gnn_main(
    const float* __restrict__ x,    // [B,S,N]
    const float* __restrict__ adj,  // [N,N]
    const float* __restrict__ w1,   // [HD]
    const float* __restrict__ b1,   // [HD]
    const float* __restrict__ w2,   // [HD, 2*HD]
    const float* __restrict__ b2,   // [HD]
    float* __restrict__ out,        // [B, N*HD] (atomic path)
    float* __restrict__ partial,    // [grid, N*HD] (partial path)
    int use_partial)
{
    __shared__ __bf16 anf[8][64][8];        // [nt*4+kk][lane][e] pre-packed B-frags, 8 KB
    __shared__ float  red[HD][NV];          // [f'][i], 8 KB
    __shared__ float  xs[4][4][NV];         // [wave][sg][j], 4 KB
    __shared__ __bf16 catg[4][NV][CATP];    // per-wave agg slices, 18 KB
    __shared__ float  w1s[HD], b1s[HD], b2s[HD], rs[NV];

    const int tid  = threadIdx.x;
    const int w    = tid >> 6;
    const int lane = tid & 63;
    const int l31  = lane & 31;
    const int lh   = lane >> 5;
    const int b    = blockIdx.x >> 6;       // /NCHUNK
    const int chk  = blockIdx.x & (NCHUNK - 1);
    const int sbase = chk * SPB + w * SPW;

    // ---- setup ----
    {
        float* rf = &red[0][0];
        #pragma unroll
        for (int q = 0; q < (HD * NV) / 256; ++q) rf[tid + q * 256] = 0.f;
    }
    if (tid < NV) {
        float s = 0.f;
        const float4* r4 = (const float4*)(adj + tid * NV);
        #pragma unroll
        for (int q = 0; q < NV / 4; ++q) { float4 v = r4[q]; s += v.x + v.y + v.z + v.w; }
        rs[tid] = 1.f / (s + 1e-8f);
    }
    if (tid < HD) { w1s[tid] = w1[tid]; b1s[tid] = b1[tid]; b2s[tid] = b2[tid]; }
    __syncthreads();

    // An B-fragments pre-packed into LDS: lane-contiguous 16B -> conflict-free b128
    #pragma unroll
    for (int q = 0; q < 2; ++q) {
        const int slot = tid + q * 256;     // 512 slots
        const int ntkk = slot >> 6, ln = slot & 63;
        const int nt = ntkk >> 2, kk = ntkk & 3;
        const int i  = nt * 32 + (ln & 31);
        const int j0 = kk * 16 + (ln >> 5) * 8;
        const float rsi = rs[i];
        const float4 a0 = *(const float4*)(adj + i * NV + j0);
        const float4 a1 = *(const float4*)(adj + i * NV + j0 + 4);
        bfv8 v;
        v[0] = (__bf16)(a0.x * rsi); v[1] = (__bf16)(a0.y * rsi);
        v[2] = (__bf16)(a0.z * rsi); v[3] = (__bf16)(a0.w * rsi);
        v[4] = (__bf16)(a1.x * rsi); v[5] = (__bf16)(a1.y * rsi);
        v[6] = (__bf16)(a1.z * rsi); v[7] = (__bf16)(a1.w * rsi);
        *(bfv8*)&anf[ntkk][ln][0] = v;
    }

    // W2 A-fragments (block-invariant): A[m=f'][k], f'=l31, k=kk*16+lh*8+e
    bfv8 wf[4];
    #pragma unroll
    for (int kk = 0; kk < 4; ++kk) {
        const int k0 = kk * 16 + lh * 8;
        const float4 a0 = *(const float4*)(w2 + l31 * (2 * HD) + k0);
        const float4 a1 = *(const float4*)(w2 + l31 * (2 * HD) + k0 + 4);
        bfv8 v;
        v[0] = (__bf16)a0.x; v[1] = (__bf16)a0.y; v[2] = (__bf16)a0.z; v[3] = (__bf16)a0.w;
        v[4] = (__bf16)a1.x; v[5] = (__bf16)a1.y; v[6] = (__bf16)a1.z; v[7] = (__bf16)a1.w;
        wf[kk] = v;
    }

    const float w1f = w1[l31];
    const float b1f = b1[l31];

    f32x16 macc0, macc1;
    #pragma unroll
    for (int r = 0; r < 16; ++r) { macc0[r] = 0.f; macc1[r] = 0.f; }

    __syncthreads();  // anf ready; last barrier before epilogue

    float* xw = &xs[w][0][0];

    for (int g = 0; g < SPW / 4; ++g) {
        // stage 4 s rows (wave-private, no barrier)
        ((float4*)xw)[lane] =
            ((const float4*)(x + ((size_t)b * SN + sbase + g * 4) * (size_t)NV))[lane];

        #pragma unroll
        for (int sg = 0; sg < 4; ++sg) {
            const float* xr = xw + sg * NV;

            // ---- A-frags for GEMM1: H[f=l31][j], j = kk*16+lh*8+e ----
            bfv8 af[4];
            #pragma unroll
            for (int kk = 0; kk < 4; ++kk) {
                const int j0 = kk * 16 + lh * 8;
                const f32x4 xa = *(const f32x4*)(xr + j0);
                const f32x4 xb = *(const f32x4*)(xr + j0 + 4);
                bfv8 v;
                v[0] = (__bf16)fmaxf(xa[0] * w1f + b1f, 0.f);
                v[1] = (__bf16)fmaxf(xa[1] * w1f + b1f, 0.f);
                v[2] = (__bf16)fmaxf(xa[2] * w1f + b1f, 0.f);
                v[3] = (__bf16)fmaxf(xa[3] * w1f + b1f, 0.f);
                v[4] = (__bf16)fmaxf(xb[0] * w1f + b1f, 0.f);
                v[5] = (__bf16)fmaxf(xb[1] * w1f + b1f, 0.f);
                v[6] = (__bf16)fmaxf(xb[2] * w1f + b1f, 0.f);
                v[7] = (__bf16)fmaxf(xb[3] * w1f + b1f, 0.f);
                af[kk] = v;
            }

            // ---- GEMM1: C[f][i] = agg, write to catg[i][f] (b64, ~2-way) ----
            #pragma unroll
            for (int nt = 0; nt < 2; ++nt) {
                f32x16 c;
                #pragma unroll
                for (int r = 0; r < 16; ++r) c[r] = 0.f;
                #pragma unroll
                for (int kk = 0; kk < 4; ++kk) {
                    const bfv8 bn = *(const bfv8*)&anf[nt * 4 + kk][lane][0];
                    c = MFMA32(af[kk], bn, c);
                }
                const int i = nt * 32 + l31;
                #pragma unroll
                for (int gq = 0; gq < 4; ++gq) {
                    const int f0 = gq * 8 + 4 * lh;   // row f = f0 + (0..3)
                    bfv4 pv;
                    pv[0] = (__bf16)c[4 * gq + 0]; pv[1] = (__bf16)c[4 * gq + 1];
                    pv[2] = (__bf16)c[4 * gq + 2]; pv[3] = (__bf16)c[4 * gq + 3];
                    *(bfv4*)&catg[w][i][f0] = pv;
                }
            }

            // ---- GEMM2: C[f'][i] = W2 . cat ----
            #pragma unroll
            for (int ih = 0; ih < 2; ++ih) {
                const int i2 = ih * 32 + l31;
                const float xi = xr[i2];
                f32x16 c;
                #pragma unroll
                for (int gq = 0; gq < 4; ++gq) {   // C init = b2[row]
                    const f32x4 bv = *(const f32x4*)&b2s[gq * 8 + 4 * lh];
                    c[4 * gq + 0] = bv[0]; c[4 * gq + 1] = bv[1];
                    c[4 * gq + 2] = bv[2]; c[4 * gq + 3] = bv[3];
                }
                #pragma unroll
                for (int kk = 0; kk < 2; ++kk) {   // h part: B[k=f][i] recomputed
                    const int f0 = kk * 16 + lh * 8;
                    const f32x4 wa = *(const f32x4*)&w1s[f0];
                    const f32x4 wb = *(const f32x4*)&w1s[f0 + 4];
                    const f32x4 ba = *(const f32x4*)&b1s[f0];
                    const f32x4 bb = *(const f32x4*)&b1s[f0 + 4];
                    bfv8 hv;
                    hv[0] = (__bf16)fmaxf(xi * wa[0] + ba[0], 0.f);
                    hv[1] = (__bf16)fmaxf(xi * wa[1] + ba[1], 0.f);
                    hv[2] = (__bf16)fmaxf(xi * wa[2] + ba[2], 0.f);
                    hv[3] = (__bf16)fmaxf(xi * wa[3] + ba[3], 0.f);
                    hv[4] = (__bf16)fmaxf(xi * wb[0] + bb[0], 0.f);
                    hv[5] = (__bf16)fmaxf(xi * wb[1] + bb[1], 0.f);
                    hv[6] = (__bf16)fmaxf(xi * wb[2] + bb[2], 0.f);
                    hv[7] = (__bf16)fmaxf(xi * wb[3] + bb[3], 0.f);
                    c = MFMA32(wf[kk], hv, c);
                }
                #pragma unroll
                for (int kk = 2; kk < 4; ++kk) {   // agg part from catg
                    const int fa0 = (kk - 2) * 16 + lh * 8;
                    const bfv4 lo = *(const bfv4*)&catg[w][i2][fa0];
                    const bfv4 hi = *(const bfv4*)&catg[w][i2][fa0 + 4];
                    bfv8 bv;
                    bv[0] = lo[0]; bv[1] = lo[1]; bv[2] = lo[2]; bv[3] = lo[3];
                    bv[4] = hi[0]; bv[5] = hi[1]; bv[6] = hi[2]; bv[7] = hi[3];
                    c = MFMA32(wf[kk], bv, c);
                }
                if (ih == 0) {
                    #pragma unroll
                    for (int r = 0; r < 16; ++r) macc0[r] += fmaxf(c[r], 0.f);
                } else {
                    #pragma unroll
                    for (int r = 0; r < 16; ++r) macc1[r] += fmaxf(c[r], 0.f);
                }
            }
        }
    }

    // ---- epilogue ----
    #pragma unroll
    for (int r = 0; r < 16; ++r) {
        const int row = (r & 3) + 8 * (r >> 2) + 4 * lh;  // f'
        atomicAdd(&red[row][l31], macc0[r]);
        atomicAdd(&red[row][l31 + 32], macc1[r]);
    }
    __syncthreads();
    const float* rf = &red[0][0];
    if (use_partial) {
        float* dst = partial + (size_t)blockIdx.x * (NV * HD);
        #pragma unroll
        for (int q = 0; q < (HD * NV) / 256; ++q) dst[tid + q * 256] = rf[tid + q * 256];
    } else {
        const float inv = 1.f / (float)SN;
        #pragma unroll
        for (int q = 0; q < (HD * NV) / 256; ++q) {
            const int e = tid + q * 256;
            const int f = e >> 6, i = e & 63;
            atomicAdd(out + (size_t)b * (NV * HD) + i * HD + f, rf[e] * inv);
        }
    }
}

__global__ __launch_bounds__(256) void gnn_reduce(
    const float* __restrict__ partial, float* __restrict__ out)
{
    const int t = blockIdx.x * 256 + threadIdx.x;   // 16*2048
    const int b = t >> 11;
    const int e = t & 2047;                          // e = f*64 + i
    const float* p = partial + (size_t)b * NCHUNK * 2048 + e;
    float s = 0.f;
    #pragma unroll 8
    for (int c = 0; c < NCHUNK; ++c) s += p[(size_t)c * 2048];
    const int f = e >> 6, i = e & 63;
    out[(size_t)b * 2048 + i * HD + f] = s * (1.f / (float)SN);
}

extern "C" void kernel_launch(void* const* d_in, const int* in_sizes, int n_in,
                              void* d_out, int out_size, void* d_ws, size_t ws_size,
                              hipStream_t stream) {
    const float* x   = (const float*)d_in[0];
    const float* adj = (const float*)d_in[1];
    const float* w1  = (const float*)d_in[2];
    const float* b1  = (const float*)d_in[3];
    const float* w2  = (const float*)d_in[4];
    const float* b2  = (const float*)d_in[5];
    float* out = (float*)d_out;

    const size_t need = (size_t)(BN * NCHUNK) * (NV * HD) * sizeof(float); // 8 MB
    const int useP = (d_ws != nullptr && ws_size >= need) ? 1 : 0;

    if (!useP) hipMemsetAsync(out, 0, (size_t)out_size * sizeof(float), stream);
    gnn_main<<<dim3(BN * NCHUNK), dim3(256), 0, stream>>>(
        x, adj, w1, b1, w2, b2, out, (float*)d_ws, useP);
    if (useP) gnn_reduce<<<dim3(BN * SN / 256), dim3(256), 0, stream>>>((float*)d_ws, out);
}

// Round 4
// 163.054 us; speedup vs baseline: 1.5300x; 1.5300x over previous
//
#include <hip/hip_runtime.h>

// GNNEncoder fused MFMA kernel, round 4 = round 3 structure with the spill fixed:
// __launch_bounds__(256,2) (R3's (256,3) capped regs at ~170, AGPR+VGPR overflowed,
// accumulators spilled to scratch -> 460 MB HBM traffic. (256,2) is the proven cap.)
#define BN 16
#define SN 2048
#define NV 64
#define HD 32
#define SPW 8                 // s per wave
#define SPB (SPW * 4)         // 32 s per block
#define NCHUNK (SN / SPB)     // 64 chunks per b -> grid 1024
#define CATP 36               // catg row stride (72 B): ~2-way LDS aliasing, free

typedef short  bf8i  __attribute__((ext_vector_type(8)));
typedef __bf16 bfv8  __attribute__((ext_vector_type(8)));
typedef __bf16 bfv4  __attribute__((ext_vector_type(4)));
typedef float  f32x16 __attribute__((ext_vector_type(16)));
typedef float  f32x4  __attribute__((ext_vector_type(4)));

#define MFMA32(a, b, c) __builtin_amdgcn_mfma_f32_32x32x16_bf16( \
    __builtin_bit_cast(bf8i, (a)), __builtin_bit_cast(bf8i, (b)), (c), 0, 0, 0)

__global__ __launch_bounds__(256, 2) void gnn_main(
    const float* __restrict__ x,    // [B,S,N]
    const float* __restrict__ adj,  // [N,N]
    const float* __restrict__ w1,   // [HD]
    const float* __restrict__ b1,   // [HD]
    const float* __restrict__ w2,   // [HD, 2*HD]
    const float* __restrict__ b2,   // [HD]
    float* __restrict__ out,        // [B, N*HD] (atomic path)
    float* __restrict__ partial,    // [grid, N*HD] (partial path)
    int use_partial)
{
    __shared__ __bf16 anf[8][64][8];        // [nt*4+kk][lane][e] pre-packed B-frags, 8 KB
    __shared__ float  red[HD][NV];          // [f'][i], 8 KB
    __shared__ float  xs[4][4][NV];         // [wave][sg][j], 4 KB
    __shared__ __bf16 catg[4][NV][CATP];    // per-wave agg slices, 18 KB
    __shared__ float  w1s[HD], b1s[HD], b2s[HD], rs[NV];

    const int tid  = threadIdx.x;
    const int w    = tid >> 6;
    const int lane = tid & 63;
    const int l31  = lane & 31;
    const int lh   = lane >> 5;
    const int b    = blockIdx.x >> 6;       // /NCHUNK
    const int chk  = blockIdx.x & (NCHUNK - 1);
    const int sbase = chk * SPB + w * SPW;

    // ---- setup ----
    {
        float* rf = &red[0][0];
        #pragma unroll
        for (int q = 0; q < (HD * NV) / 256; ++q) rf[tid + q * 256] = 0.f;
    }
    if (tid < NV) {
        float s = 0.f;
        const float4* r4 = (const float4*)(adj + tid * NV);
        #pragma unroll
        for (int q = 0; q < NV / 4; ++q) { float4 v = r4[q]; s += v.x + v.y + v.z + v.w; }
        rs[tid] = 1.f / (s + 1e-8f);
    }
    if (tid < HD) { w1s[tid] = w1[tid]; b1s[tid] = b1[tid]; b2s[tid] = b2[tid]; }
    __syncthreads();

    // An B-fragments pre-packed into LDS: lane-contiguous 16B -> conflict-free b128
    #pragma unroll
    for (int q = 0; q < 2; ++q) {
        const int slot = tid + q * 256;     // 512 slots
        const int ntkk = slot >> 6, ln = slot & 63;
        const int nt = ntkk >> 2, kk = ntkk & 3;
        const int i  = nt * 32 + (ln & 31);
        const int j0 = kk * 16 + (ln >> 5) * 8;
        const float rsi = rs[i];
        const float4 a0 = *(const float4*)(adj + i * NV + j0);
        const float4 a1 = *(const float4*)(adj + i * NV + j0 + 4);
        bfv8 v;
        v[0] = (__bf16)(a0.x * rsi); v[1] = (__bf16)(a0.y * rsi);
        v[2] = (__bf16)(a0.z * rsi); v[3] = (__bf16)(a0.w * rsi);
        v[4] = (__bf16)(a1.x * rsi); v[5] = (__bf16)(a1.y * rsi);
        v[6] = (__bf16)(a1.z * rsi); v[7] = (__bf16)(a1.w * rsi);
        *(bfv8*)&anf[ntkk][ln][0] = v;
    }

    // W2 A-fragments (block-invariant): A[m=f'][k], f'=l31, k=kk*16+lh*8+e
    bfv8 wf[4];
    #pragma unroll
    for (int kk = 0; kk < 4; ++kk) {
        const int k0 = kk * 16 + lh * 8;
        const float4 a0 = *(const float4*)(w2 + l31 * (2 * HD) + k0);
        const float4 a1 = *(const float4*)(w2 + l31 * (2 * HD) + k0 + 4);
        bfv8 v;
        v[0] = (__bf16)a0.x; v[1] = (__bf16)a0.y; v[2] = (__bf16)a0.z; v[3] = (__bf16)a0.w;
        v[4] = (__bf16)a1.x; v[5] = (__bf16)a1.y; v[6] = (__bf16)a1.z; v[7] = (__bf16)a1.w;
        wf[kk] = v;
    }

    const float w1f = w1[l31];
    const float b1f = b1[l31];

    f32x16 macc0, macc1;
    #pragma unroll
    for (int r = 0; r < 16; ++r) { macc0[r] = 0.f; macc1[r] = 0.f; }

    __syncthreads();  // anf ready; last barrier before epilogue

    float* xw = &xs[w][0][0];

    for (int g = 0; g < SPW / 4; ++g) {
        // stage 4 s rows (wave-private, no barrier)
        ((float4*)xw)[lane] =
            ((const float4*)(x + ((size_t)b * SN + sbase + g * 4) * (size_t)NV))[lane];

        #pragma unroll
        for (int sg = 0; sg < 4; ++sg) {
            const float* xr = xw + sg * NV;

            // ---- A-frags for GEMM1: H[f=l31][j], j = kk*16+lh*8+e ----
            bfv8 af[4];
            #pragma unroll
            for (int kk = 0; kk < 4; ++kk) {
                const int j0 = kk * 16 + lh * 8;
                const f32x4 xa = *(const f32x4*)(xr + j0);
                const f32x4 xb = *(const f32x4*)(xr + j0 + 4);
                bfv8 v;
                v[0] = (__bf16)fmaxf(xa[0] * w1f + b1f, 0.f);
                v[1] = (__bf16)fmaxf(xa[1] * w1f + b1f, 0.f);
                v[2] = (__bf16)fmaxf(xa[2] * w1f + b1f, 0.f);
                v[3] = (__bf16)fmaxf(xa[3] * w1f + b1f, 0.f);
                v[4] = (__bf16)fmaxf(xb[0] * w1f + b1f, 0.f);
                v[5] = (__bf16)fmaxf(xb[1] * w1f + b1f, 0.f);
                v[6] = (__bf16)fmaxf(xb[2] * w1f + b1f, 0.f);
                v[7] = (__bf16)fmaxf(xb[3] * w1f + b1f, 0.f);
                af[kk] = v;
            }

            // ---- GEMM1: C[f][i] = agg, write to catg[i][f] (b64, ~2-way) ----
            #pragma unroll
            for (int nt = 0; nt < 2; ++nt) {
                f32x16 c;
                #pragma unroll
                for (int r = 0; r < 16; ++r) c[r] = 0.f;
                #pragma unroll
                for (int kk = 0; kk < 4; ++kk) {
                    const bfv8 bn = *(const bfv8*)&anf[nt * 4 + kk][lane][0];
                    c = MFMA32(af[kk], bn, c);
                }
                const int i = nt * 32 + l31;
                #pragma unroll
                for (int gq = 0; gq < 4; ++gq) {
                    const int f0 = gq * 8 + 4 * lh;   // row f = f0 + (0..3)
                    bfv4 pv;
                    pv[0] = (__bf16)c[4 * gq + 0]; pv[1] = (__bf16)c[4 * gq + 1];
                    pv[2] = (__bf16)c[4 * gq + 2]; pv[3] = (__bf16)c[4 * gq + 3];
                    *(bfv4*)&catg[w][i][f0] = pv;
                }
            }

            // ---- GEMM2: C[f'][i] = W2 . cat ----
            #pragma unroll
            for (int ih = 0; ih < 2; ++ih) {
                const int i2 = ih * 32 + l31;
                const float xi = xr[i2];
                f32x16 c;
                #pragma unroll
                for (int gq = 0; gq < 4; ++gq) {   // C init = b2[row]
                    const f32x4 bv = *(const f32x4*)&b2s[gq * 8 + 4 * lh];
                    c[4 * gq + 0] = bv[0]; c[4 * gq + 1] = bv[1];
                    c[4 * gq + 2] = bv[2]; c[4 * gq + 3] = bv[3];
                }
                #pragma unroll
                for (int kk = 0; kk < 2; ++kk) {   // h part: B[k=f][i] recomputed
                    const int f0 = kk * 16 + lh * 8;
                    const f32x4 wa = *(const f32x4*)&w1s[f0];
                    const f32x4 wb = *(const f32x4*)&w1s[f0 + 4];
                    const f32x4 ba = *(const f32x4*)&b1s[f0];
                    const f32x4 bb = *(const f32x4*)&b1s[f0 + 4];
                    bfv8 hv;
                    hv[0] = (__bf16)fmaxf(xi * wa[0] + ba[0], 0.f);
                    hv[1] = (__bf16)fmaxf(xi * wa[1] + ba[1], 0.f);
                    hv[2] = (__bf16)fmaxf(xi * wa[2] + ba[2], 0.f);
                    hv[3] = (__bf16)fmaxf(xi * wa[3] + ba[3], 0.f);
                    hv[4] = (__bf16)fmaxf(xi * wb[0] + bb[0], 0.f);
                    hv[5] = (__bf16)fmaxf(xi * wb[1] + bb[1], 0.f);
                    hv[6] = (__bf16)fmaxf(xi * wb[2] + bb[2], 0.f);
                    hv[7] = (__bf16)fmaxf(xi * wb[3] + bb[3], 0.f);
                    c = MFMA32(wf[kk], hv, c);
                }
                #pragma unroll
                for (int kk = 2; kk < 4; ++kk) {   // agg part from catg
                    const int fa0 = (kk - 2) * 16 + lh * 8;
                    const bfv4 lo = *(const bfv4*)&catg[w][i2][fa0];
                    const bfv4 hi = *(const bfv4*)&catg[w][i2][fa0 + 4];
                    bfv8 bv;
                    bv[0] = lo[0]; bv[1] = lo[1]; bv[2] = lo[2]; bv[3] = lo[3];
                    bv[4] = hi[0]; bv[5] = hi[1]; bv[6] = hi[2]; bv[7] = hi[3];
                    c = MFMA32(wf[kk], bv, c);
                }
                if (ih == 0) {
                    #pragma unroll
                    for (int r = 0; r < 16; ++r) macc0[r] += fmaxf(c[r], 0.f);
                } else {
                    #pragma unroll
                    for (int r = 0; r < 16; ++r) macc1[r] += fmaxf(c[r], 0.f);
                }
            }
        }
    }

    // ---- epilogue ----
    #pragma unroll
    for (int r = 0; r < 16; ++r) {
        const int row = (r & 3) + 8 * (r >> 2) + 4 * lh;  // f'
        atomicAdd(&red[row][l31], macc0[r]);
        atomicAdd(&red[row][l31 + 32], macc1[r]);
    }
    __syncthreads();
    const float* rf = &red[0][0];
    if (use_partial) {
        float* dst = partial + (size_t)blockIdx.x * (NV * HD);
        #pragma unroll
        for (int q = 0; q < (HD * NV) / 256; ++q) dst[tid + q * 256] = rf[tid + q * 256];
    } else {
        const float inv = 1.f / (float)SN;
        #pragma unroll
        for (int q = 0; q < (HD * NV) / 256; ++q) {
            const int e = tid + q * 256;
            const int f = e >> 6, i = e & 63;
            atomicAdd(out + (size_t)b * (NV * HD) + i * HD + f, rf[e] * inv);
        }
    }
}

__global__ __launch_bounds__(256) void gnn_reduce(
    const float* __restrict__ partial, float* __restrict__ out)
{
    const int t = blockIdx.x * 256 + threadIdx.x;   // 16*2048
    const int b = t >> 11;
    const int e = t & 2047;                          // e = f*64 + i
    const float* p = partial + (size_t)b * NCHUNK * 2048 + e;
    float s = 0.f;
    #pragma unroll 8
    for (int c = 0; c < NCHUNK; ++c) s += p[(size_t)c * 2048];
    const int f = e >> 6, i = e & 63;
    out[(size_t)b * 2048 + i * HD + f] = s * (1.f / (float)SN);
}

extern "C" void kernel_launch(void* const* d_in, const int* in_sizes, int n_in,
                              void* d_out, int out_size, void* d_ws, size_t ws_size,
                              hipStream_t stream) {
    const float* x   = (const float*)d_in[0];
    const float* adj = (const float*)d_in[1];
    const float* w1  = (const float*)d_in[2];
    const float* b1  = (const float*)d_in[3];
    const float* w2  = (const float*)d_in[4];
    const float* b2  = (const float*)d_in[5];
    float* out = (float*)d_out;

    const size_t need = (size_t)(BN * NCHUNK) * (NV * HD) * sizeof(float); // 8 MB
    const int useP = (d_ws != nullptr && ws_size >= need) ? 1 : 0;

    if (!useP) hipMemsetAsync(out, 0, (size_t)out_size * sizeof(float), stream);
    gnn_main<<<dim3(BN * NCHUNK), dim3(256), 0, stream>>>(
        x, adj, w1, b1, w2, b2, out, (float*)d_ws, useP);
    if (useP) gnn_reduce<<<dim3(BN * SN / 256), dim3(256), 0, stream>>>((float*)d_ws, out);
}

// Round 5
// 140.750 us; speedup vs baseline: 1.7725x; 1.1585x over previous
//
#include <hip/hip_runtime.h>

// GNNEncoder fused MFMA kernel, round 5 = round 4 with scheduling restrained:
// #pragma unroll 1 on g/sg/nt loops. R4's fully-unrolled body let the scheduler
// keep several f32x16 MFMA C-tiles + fragment sets live at once -> unified
// VGPR+AGPR overflow -> ~81 MB of scratch writebacks (WRITE_SIZE 89 MB vs 8 MB
// ideal). Serializing the phases caps live state at ~100 regs.
#define BN 16
#define SN 2048
#define NV 64
#define HD 32
#define SPW 8                 // s per wave
#define SPB (SPW * 4)         // 32 s per block
#define NCHUNK (SN / SPB)     // 64 chunks per b -> grid 1024
#define CATP 36               // catg row stride (72 B): ~2-way LDS aliasing, free

typedef short  bf8i  __attribute__((ext_vector_type(8)));
typedef __bf16 bfv8  __attribute__((ext_vector_type(8)));
typedef __bf16 bfv4  __attribute__((ext_vector_type(4)));
typedef float  f32x16 __attribute__((ext_vector_type(16)));
typedef float  f32x4  __attribute__((ext_vector_type(4)));

#define MFMA32(a, b, c) __builtin_amdgcn_mfma_f32_32x32x16_bf16( \
    __builtin_bit_cast(bf8i, (a)), __builtin_bit_cast(bf8i, (b)), (c), 0, 0, 0)

__global__ __launch_bounds__(256, 2) void gnn_main(
    const float* __restrict__ x,    // [B,S,N]
    const float* __restrict__ adj,  // [N,N]
    const float* __restrict__ w1,   // [HD]
    const float* __restrict__ b1,   // [HD]
    const float* __restrict__ w2,   // [HD, 2*HD]
    const float* __restrict__ b2,   // [HD]
    float* __restrict__ out,        // [B, N*HD] (atomic path)
    float* __restrict__ partial,    // [grid, N*HD] (partial path)
    int use_partial)
{
    __shared__ __bf16 anf[8][64][8];        // [nt*4+kk][lane][e] pre-packed B-frags, 8 KB
    __shared__ float  red[HD][NV];          // [f'][i], 8 KB
    __shared__ float  xs[4][4][NV];         // [wave][sg][j], 4 KB
    __shared__ __bf16 catg[4][NV][CATP];    // per-wave agg slices, 18 KB
    __shared__ float  w1s[HD], b1s[HD], b2s[HD], rs[NV];

    const int tid  = threadIdx.x;
    const int w    = tid >> 6;
    const int lane = tid & 63;
    const int l31  = lane & 31;
    const int lh   = lane >> 5;
    const int b    = blockIdx.x >> 6;       // /NCHUNK
    const int chk  = blockIdx.x & (NCHUNK - 1);
    const int sbase = chk * SPB + w * SPW;

    // ---- setup ----
    {
        float* rf = &red[0][0];
        #pragma unroll
        for (int q = 0; q < (HD * NV) / 256; ++q) rf[tid + q * 256] = 0.f;
    }
    if (tid < NV) {
        float s = 0.f;
        const float4* r4 = (const float4*)(adj + tid * NV);
        #pragma unroll
        for (int q = 0; q < NV / 4; ++q) { float4 v = r4[q]; s += v.x + v.y + v.z + v.w; }
        rs[tid] = 1.f / (s + 1e-8f);
    }
    if (tid < HD) { w1s[tid] = w1[tid]; b1s[tid] = b1[tid]; b2s[tid] = b2[tid]; }
    __syncthreads();

    // An B-fragments pre-packed into LDS: lane-contiguous 16B -> conflict-free b128
    #pragma unroll
    for (int q = 0; q < 2; ++q) {
        const int slot = tid + q * 256;     // 512 slots
        const int ntkk = slot >> 6, ln = slot & 63;
        const int nt = ntkk >> 2, kk = ntkk & 3;
        const int i  = nt * 32 + (ln & 31);
        const int j0 = kk * 16 + (ln >> 5) * 8;
        const float rsi = rs[i];
        const float4 a0 = *(const float4*)(adj + i * NV + j0);
        const float4 a1 = *(const float4*)(adj + i * NV + j0 + 4);
        bfv8 v;
        v[0] = (__bf16)(a0.x * rsi); v[1] = (__bf16)(a0.y * rsi);
        v[2] = (__bf16)(a0.z * rsi); v[3] = (__bf16)(a0.w * rsi);
        v[4] = (__bf16)(a1.x * rsi); v[5] = (__bf16)(a1.y * rsi);
        v[6] = (__bf16)(a1.z * rsi); v[7] = (__bf16)(a1.w * rsi);
        *(bfv8*)&anf[ntkk][ln][0] = v;
    }

    // W2 A-fragments (block-invariant): A[m=f'][k], f'=l31, k=kk*16+lh*8+e
    bfv8 wf[4];
    #pragma unroll
    for (int kk = 0; kk < 4; ++kk) {
        const int k0 = kk * 16 + lh * 8;
        const float4 a0 = *(const float4*)(w2 + l31 * (2 * HD) + k0);
        const float4 a1 = *(const float4*)(w2 + l31 * (2 * HD) + k0 + 4);
        bfv8 v;
        v[0] = (__bf16)a0.x; v[1] = (__bf16)a0.y; v[2] = (__bf16)a0.z; v[3] = (__bf16)a0.w;
        v[4] = (__bf16)a1.x; v[5] = (__bf16)a1.y; v[6] = (__bf16)a1.z; v[7] = (__bf16)a1.w;
        wf[kk] = v;
    }

    const float w1f = w1[l31];
    const float b1f = b1[l31];

    f32x16 macc0, macc1;
    #pragma unroll
    for (int r = 0; r < 16; ++r) { macc0[r] = 0.f; macc1[r] = 0.f; }

    __syncthreads();  // anf ready; last barrier before epilogue

    float* xw = &xs[w][0][0];

    #pragma unroll 1
    for (int g = 0; g < SPW / 4; ++g) {
        // stage 4 s rows (wave-private, no barrier)
        ((float4*)xw)[lane] =
            ((const float4*)(x + ((size_t)b * SN + sbase + g * 4) * (size_t)NV))[lane];

        #pragma unroll 1
        for (int sg = 0; sg < 4; ++sg) {
            const float* xr = xw + sg * NV;

            // ---- A-frags for GEMM1: H[f=l31][j], j = kk*16+lh*8+e ----
            bfv8 af[4];
            #pragma unroll
            for (int kk = 0; kk < 4; ++kk) {
                const int j0 = kk * 16 + lh * 8;
                const f32x4 xa = *(const f32x4*)(xr + j0);
                const f32x4 xb = *(const f32x4*)(xr + j0 + 4);
                bfv8 v;
                v[0] = (__bf16)fmaxf(xa[0] * w1f + b1f, 0.f);
                v[1] = (__bf16)fmaxf(xa[1] * w1f + b1f, 0.f);
                v[2] = (__bf16)fmaxf(xa[2] * w1f + b1f, 0.f);
                v[3] = (__bf16)fmaxf(xa[3] * w1f + b1f, 0.f);
                v[4] = (__bf16)fmaxf(xb[0] * w1f + b1f, 0.f);
                v[5] = (__bf16)fmaxf(xb[1] * w1f + b1f, 0.f);
                v[6] = (__bf16)fmaxf(xb[2] * w1f + b1f, 0.f);
                v[7] = (__bf16)fmaxf(xb[3] * w1f + b1f, 0.f);
                af[kk] = v;
            }

            // ---- GEMM1: C[f][i] = agg, write to catg[i][f] (b64, ~2-way) ----
            #pragma unroll 1
            for (int nt = 0; nt < 2; ++nt) {
                f32x16 c;
                #pragma unroll
                for (int r = 0; r < 16; ++r) c[r] = 0.f;
                #pragma unroll
                for (int kk = 0; kk < 4; ++kk) {
                    const bfv8 bn = *(const bfv8*)&anf[nt * 4 + kk][lane][0];
                    c = MFMA32(af[kk], bn, c);
                }
                const int i = nt * 32 + l31;
                #pragma unroll
                for (int gq = 0; gq < 4; ++gq) {
                    const int f0 = gq * 8 + 4 * lh;   // row f = f0 + (0..3)
                    bfv4 pv;
                    pv[0] = (__bf16)c[4 * gq + 0]; pv[1] = (__bf16)c[4 * gq + 1];
                    pv[2] = (__bf16)c[4 * gq + 2]; pv[3] = (__bf16)c[4 * gq + 3];
                    *(bfv4*)&catg[w][i][f0] = pv;
                }
            }

            // ---- GEMM2: C[f'][i] = W2 . cat ----
            #pragma unroll
            for (int ih = 0; ih < 2; ++ih) {
                const int i2 = ih * 32 + l31;
                const float xi = xr[i2];
                f32x16 c;
                #pragma unroll
                for (int gq = 0; gq < 4; ++gq) {   // C init = b2[row]
                    const f32x4 bv = *(const f32x4*)&b2s[gq * 8 + 4 * lh];
                    c[4 * gq + 0] = bv[0]; c[4 * gq + 1] = bv[1];
                    c[4 * gq + 2] = bv[2]; c[4 * gq + 3] = bv[3];
                }
                #pragma unroll
                for (int kk = 0; kk < 2; ++kk) {   // h part: B[k=f][i] recomputed
                    const int f0 = kk * 16 + lh * 8;
                    const f32x4 wa = *(const f32x4*)&w1s[f0];
                    const f32x4 wb = *(const f32x4*)&w1s[f0 + 4];
                    const f32x4 ba = *(const f32x4*)&b1s[f0];
                    const f32x4 bb = *(const f32x4*)&b1s[f0 + 4];
                    bfv8 hv;
                    hv[0] = (__bf16)fmaxf(xi * wa[0] + ba[0], 0.f);
                    hv[1] = (__bf16)fmaxf(xi * wa[1] + ba[1], 0.f);
                    hv[2] = (__bf16)fmaxf(xi * wa[2] + ba[2], 0.f);
                    hv[3] = (__bf16)fmaxf(xi * wa[3] + ba[3], 0.f);
                    hv[4] = (__bf16)fmaxf(xi * wb[0] + bb[0], 0.f);
                    hv[5] = (__bf16)fmaxf(xi * wb[1] + bb[1], 0.f);
                    hv[6] = (__bf16)fmaxf(xi * wb[2] + bb[2], 0.f);
                    hv[7] = (__bf16)fmaxf(xi * wb[3] + bb[3], 0.f);
                    c = MFMA32(wf[kk], hv, c);
                }
                #pragma unroll
                for (int kk = 2; kk < 4; ++kk) {   // agg part from catg
                    const int fa0 = (kk - 2) * 16 + lh * 8;
                    const bfv4 lo = *(const bfv4*)&catg[w][i2][fa0];
                    const bfv4 hi = *(const bfv4*)&catg[w][i2][fa0 + 4];
                    bfv8 bv;
                    bv[0] = lo[0]; bv[1] = lo[1]; bv[2] = lo[2]; bv[3] = lo[3];
                    bv[4] = hi[0]; bv[5] = hi[1]; bv[6] = hi[2]; bv[7] = hi[3];
                    c = MFMA32(wf[kk], bv, c);
                }
                if (ih == 0) {
                    #pragma unroll
                    for (int r = 0; r < 16; ++r) macc0[r] += fmaxf(c[r], 0.f);
                } else {
                    #pragma unroll
                    for (int r = 0; r < 16; ++r) macc1[r] += fmaxf(c[r], 0.f);
                }
            }
        }
    }

    // ---- epilogue ----
    #pragma unroll
    for (int r = 0; r < 16; ++r) {
        const int row = (r & 3) + 8 * (r >> 2) + 4 * lh;  // f'
        atomicAdd(&red[row][l31], macc0[r]);
        atomicAdd(&red[row][l31 + 32], macc1[r]);
    }
    __syncthreads();
    const float* rf = &red[0][0];
    if (use_partial) {
        float* dst = partial + (size_t)blockIdx.x * (NV * HD);
        #pragma unroll
        for (int q = 0; q < (HD * NV) / 256; ++q) dst[tid + q * 256] = rf[tid + q * 256];
    } else {
        const float inv = 1.f / (float)SN;
        #pragma unroll
        for (int q = 0; q < (HD * NV) / 256; ++q) {
            const int e = tid + q * 256;
            const int f = e >> 6, i = e & 63;
            atomicAdd(out + (size_t)b * (NV * HD) + i * HD + f, rf[e] * inv);
        }
    }
}

__global__ __launch_bounds__(256) void gnn_reduce(
    const float* __restrict__ partial, float* __restrict__ out)
{
    const int t = blockIdx.x * 256 + threadIdx.x;   // 16*2048
    const int b = t >> 11;
    const int e = t & 2047;                          // e = f*64 + i
    const float* p = partial + (size_t)b * NCHUNK * 2048 + e;
    float s = 0.f;
    #pragma unroll 8
    for (int c = 0; c < NCHUNK; ++c) s += p[(size_t)c * 2048];
    const int f = e >> 6, i = e & 63;
    out[(size_t)b * 2048 + i * HD + f] = s * (1.f / (float)SN);
}

extern "C" void kernel_launch(void* const* d_in, const int* in_sizes, int n_in,
                              void* d_out, int out_size, void* d_ws, size_t ws_size,
                              hipStream_t stream) {
    const float* x   = (const float*)d_in[0];
    const float* adj = (const float*)d_in[1];
    const float* w1  = (const float*)d_in[2];
    const float* b1  = (const float*)d_in[3];
    const float* w2  = (const float*)d_in[4];
    const float* b2  = (const float*)d_in[5];
    float* out = (float*)d_out;

    const size_t need = (size_t)(BN * NCHUNK) * (NV * HD) * sizeof(float); // 8 MB
    const int useP = (d_ws != nullptr && ws_size >= need) ? 1 : 0;

    if (!useP) hipMemsetAsync(out, 0, (size_t)out_size * sizeof(float), stream);
    gnn_main<<<dim3(BN * NCHUNK), dim3(256), 0, stream>>>(
        x, adj, w1, b1, w2, b2, out, (float*)d_ws, useP);
    if (useP) gnn_reduce<<<dim3(BN * SN / 256), dim3(256), 0, stream>>>((float*)d_ws, out);
}